// Round 6
// baseline (438.342 us; speedup 1.0000x reference)
//
#include <hip/hip_runtime.h>
#include <cstdint>

#define PI_F 3.14159265358979323846f

// ===========================================================================
// Compile-time reproduction of np.random.RandomState(seed).standard_normal
// (MT19937 + legacy Marsaglia polar gauss).
// r11 packing: cg rows padded to mult-of-4 floats (zero-filled) -> cg[1104];
// Dtab slices padded likewise (192 padded slots). tabC[t] = e | x<<8 |
// dmap<<16 (dmap = padded writeback slot). tabD[ei] = {goff_p|n4<<16, doff_p,
// p1, p2} where n4 = padded_len/4. eTab[41] = comb|l3<<8 for the pre-kernel.
// ===========================================================================
namespace cgc {

constexpr double csqrt(double x) {
  if (x <= 0.0) return 0.0;
  double m = x; int e = 0;
  while (m >= 4.0) { m *= 0.25; e++; }
  while (m < 1.0) { m *= 4.0; e--; }
  double g = 1.5;
  for (int i = 0; i < 16; i++) g = 0.5 * (g + m / g);
  double s = g;
  if (e > 0) for (int i = 0; i < e; i++) s *= 2.0;
  else       for (int i = 0; i < -e; i++) s *= 0.5;
  return s;
}

constexpr double clog(double x) {
  int k = 0;
  double m = x;
  while (m < 0.7071067811865476) { m *= 2.0; k--; }
  while (m > 1.4142135623730951) { m *= 0.5; k++; }
  double t = (m - 1.0) / (m + 1.0), t2 = t * t, s = 0.0, p = t;
  for (int i = 0; i < 27; i++) { s += p / (double)(2 * i + 1); p *= t2; }
  return 2.0 * s + (double)k * 0.6931471805599453;
}

struct RS { uint32_t mt[624]; int mti; bool has; double g; };

constexpr void rs_seed(RS& r, uint32_t s) {
  for (int i = 0; i < 624; i++) { r.mt[i] = s; s = 1812433253u * (s ^ (s >> 30)) + (uint32_t)i + 1u; }
  r.mti = 624; r.has = false; r.g = 0.0;
}
constexpr uint32_t rs_next(RS& r) {
  if (r.mti >= 624) {
    for (int i = 0; i < 624; i++) {
      uint32_t y = (r.mt[i] & 0x80000000u) | (r.mt[(i + 1) % 624] & 0x7fffffffu);
      r.mt[i] = r.mt[(i + 397) % 624] ^ (y >> 1) ^ ((y & 1u) ? 0x9908b0dfu : 0u);
    }
    r.mti = 0;
  }
  uint32_t y = r.mt[r.mti++];
  y ^= y >> 11; y ^= (y << 7) & 0x9d2c5680u; y ^= (y << 15) & 0xefc60000u; y ^= y >> 18;
  return y;
}
constexpr double rs_dbl(RS& r) {
  uint32_t a = rs_next(r) >> 5, b = rs_next(r) >> 6;
  return ((double)a * 67108864.0 + (double)b) / 9007199254740992.0;
}
constexpr double rs_gauss(RS& r) {
  if (r.has) { r.has = false; return r.g; }
  double x1 = 0, x2 = 0, r2 = 0;
  do {
    x1 = 2.0 * rs_dbl(r) - 1.0;
    x2 = 2.0 * rs_dbl(r) - 1.0;
    r2 = x1 * x1 + x2 * x2;
  } while (r2 >= 1.0 || r2 == 0.0);
  double f = csqrt(-2.0 * clog(r2) / r2);
  r.g = f * x1; r.has = true;
  return f * x2;
}

struct Tab { float v[228]; };

constexpr Tab gen(int l1, int l2, int l3) {
  Tab t{};
  RS r{};
  rs_seed(r, (uint32_t)(1000 + l1 * 100 + l2 * 10 + l3));
  int sz = (2 * l1 + 1) * (2 * l2 + 1) * (2 * l3 + 1);
  for (int k = 0; k < sz; k++) t.v[k] = (float)rs_gauss(r);
  return t;
}

constexpr Tab T000 = gen(0,0,0);
constexpr Tab T101 = gen(1,0,1);
constexpr Tab T110 = gen(1,1,0);
constexpr Tab T111 = gen(1,1,1);
constexpr Tab T112 = gen(1,1,2);
constexpr Tab T202 = gen(2,0,2);
constexpr Tab T211 = gen(2,1,1);
constexpr Tab T212 = gen(2,1,2);
constexpr Tab T213 = gen(2,1,3);
constexpr Tab T220 = gen(2,2,0);
constexpr Tab T221 = gen(2,2,1);
constexpr Tab T222 = gen(2,2,2);
constexpr Tab T223 = gen(2,2,3);
constexpr Tab T224 = gen(2,2,4);

struct alignas(16) Stage {
  int tabD[133 * 4];   // goff_p|n4<<16, doff_p, p1, p2
  float cg[1104];      // padded rows, zero-filled pads
  uint32_t tabC[133];  // e | x<<8 | dmap<<16
  int eTab[48];        // comb | l3<<8
  int ne;              // == 41
};

constexpr Stage make_stage() {
  Stage S{};
  S.ne = 0;
  const Tab* tabs[14] = {&T000,&T101,&T110,&T111,&T112,&T202,&T211,&T212,&T213,
                         &T220,&T221,&T222,&T223,&T224};
  const int KL[14][3] = {{0,0,0},{1,0,1},{1,1,0},{1,1,1},{1,1,2},{2,0,2},{2,1,1},
                         {2,1,2},{2,1,3},{2,2,0},{2,2,1},{2,2,2},{2,2,3},{2,2,4}};
  const int kBk[6][2] = {{0,0},{1,0},{1,1},{2,0},{2,1},{2,2}};

  int cgbase_p[6] = {}, dbase[6] = {}, dbase_p[6] = {}, xlenA[6] = {}, pxlenA[6] = {};
  int offp = 0, doff = 0, doffp = 0;
  for (int bk = 0; bk < 6; bk++) {
    int l1 = kBk[bk][0], l2 = kBk[bk][1];
    int M = 2 * l1 + 1, N = 2 * l2 + 1;
    int Ar = (l1 == 0) ? 3 : (l1 == 1) ? 2 : 1;
    int Br = (l2 == 0) ? 3 : (l2 == 1) ? 2 : 1;
    int xs[25] = {}, xl3[25] = {}, xa[25] = {};
    int cnt = 0;
    for (int l3 = l1 - l2; l3 <= l1 + l2; l3++)
      for (int a = 0; a < 2 * l3 + 1; a++) {
        xs[cnt] = l3 * l3 + a; xl3[cnt] = l3; xa[cnt] = a; cnt++;
      }
    int xlen = cnt;
    int pxlen = ((xlen + 3) / 4) * 4;
    xlenA[bk] = xlen; pxlenA[bk] = pxlen;
    cgbase_p[bk] = offp; dbase[bk] = doff; dbase_p[bk] = doffp;
    for (int mn = 0; mn < M * N; mn++)
      for (int xi = 0; xi < xlen; xi++) {
        int l3 = xl3[xi], K3 = 2 * l3 + 1, ti = 0;
        for (int c = 0; c < 14; c++)
          if (KL[c][0] == l1 && KL[c][1] == l2 && KL[c][2] == l3) ti = c;
        S.cg[offp + mn * pxlen + xi] = tabs[ti]->v[mn * K3 + xa[xi]];
      }
    offp += M * N * pxlen;
    for (int q = 0; q < Ar * Br; q++) {
      int a = q / Br, b = q % Br;
      int u = (l1 == 0) ? a : (l1 == 1) ? 3 + a : 5;
      int v = (l2 == 0) ? b : (l2 == 1) ? 3 + b : 5;
      int comb = u * 6 + v;
      for (int xi = 0; xi < xlen; xi++) {
        int key = comb | (xl3[xi] << 8);
        int id = -1;
        for (int s = 0; s < S.ne; s++) if (S.eTab[s] == key) { id = s; break; }
        if (id < 0) { id = S.ne; S.eTab[S.ne] = key; S.ne++; }
        int dmap = dbase_p[bk] + q * pxlen + xi;  // padded writeback slot
        S.tabC[doff + q * xlen + xi] = (uint32_t)(id | (xs[xi] << 8) | (dmap << 16));
      }
    }
    doff += Ar * Br * xlen;
    doffp += Ar * Br * pxlen;
  }
  const int ord[6] = {5, 4, 2, 3, 1, 0};  // big xlen first
  int ei = 0;
  for (int bo = 0; bo < 6; bo++) {
    int bk = ord[bo];
    int l1 = kBk[bk][0], l2 = kBk[bk][1];
    int M = 2 * l1 + 1, N = 2 * l2 + 1;
    int Ar = (l1 == 0) ? 3 : (l1 == 1) ? 2 : 1;
    int Br = (l2 == 0) ? 3 : (l2 == 1) ? 2 : 1;
    int rb1 = (l1 == 0) ? 0 : (l1 == 1) ? 3 : 9;
    int rb2 = (l2 == 0) ? 0 : (l2 == 1) ? 3 : 9;
    int colDim = N * Br, pxlen = pxlenA[bk];
    for (int e = 0; e < M * N * Ar * Br; e++) {
      int b = e % Br, t2 = e / Br;
      int a = t2 % Ar; t2 /= Ar;
      int n = t2 % N, m = t2 / N;
      int mn = m * N + n, q = a * Br + b;
      int ri = e / colDim, ci = e % colDim;
      int p1 = (rb1 + ri) * 14 + (rb2 + ci);
      int p2 = (l1 == l2) ? p1 : ((rb2 + ci) * 14 + (rb1 + ri));
      S.tabD[4 * ei + 0] = (cgbase_p[bk] + mn * pxlen) | ((pxlen / 4) << 16);
      S.tabD[4 * ei + 1] = dbase_p[bk] + q * pxlen;
      S.tabD[4 * ei + 2] = p1;
      S.tabD[4 * ei + 3] = p2;
      ei++;
    }
  }
  return S;
}

constexpr Stage ST = make_stage();
static_assert(ST.ne == 41, "expected 41 distinct (comb,l3) pairs");

}  // namespace cgc

__device__ const cgc::Stage g_tab = cgc::ST;

#define NE 41
#define VT_FLOATS (100 * NE * 16)   // 65600
#define WT_FLOATS 2560              // transposed w_rad
#define SBD_LEN 192                 // padded Dtab slots

// align-4 vector types for unaligned global float4/float2 loads
typedef float v4f __attribute__((vector_size(16), aligned(4)));
typedef float v2f __attribute__((vector_size(8), aligned(4)));

// ===========================================================================
// r11: kill the two serial chains the r10 post-mortem exposed.
//  (1) D' scalar LDS dots (214 ds_read_b32/wave) -> padded 16B-aligned rows
//      for cg and Dtab => 2x ds_read_b128 + 4 FMA per step (64 b128/wave).
//      Padded Dtab slices also make sbD reads wave-uniform (broadcast).
//  (2) g-loop 160 scalar global loads/lane -> w_rad transposed in pre-kernel
//      to wt[l][kq][f][4]; lane reads 8 float4 per l (40 VMEM insts total).
//      rbf broadcast once into 32 regs via shfl.
// sbD (192 floats) overlays sb[200..392] after h is dead; LDS 30016B -> still
// 5 blocks/CU. Pads zero-filled so extra MACs are no-ops.
// ===========================================================================
#define PSTRIDE 400   // h rows x=0..24 at 0..399; sbD overlays 200..391
#define SBD_OFF 200

__global__ __launch_bounds__(256) void vtab_kernel(
    const float* __restrict__ weight, const float* __restrict__ w_rad,
    const float* __restrict__ s_colg, const float* __restrict__ p_colg,
    const float* __restrict__ d_colg, float* __restrict__ ws) {
  int idx = blockIdx.x * 256 + threadIdx.x;
  if (idx < VT_FLOATS) {
    // vt[row][e][c] = sum_f w6[comb][f] * (W[t1,t2]+W[t2,t1])[l3][f][c]
    int c = idx & 15;
    int rest = idx >> 4;
    int e = rest % NE, row = rest / NE;
    int t1 = row / 10, t2 = row - t1 * 10;
    int et = g_tab.eTab[e];
    int comb = et & 255, l3 = et >> 8;
    int u = comb / 6, v = comb % 6;
    const float* wr1 = weight + ((size_t)row * 5 + l3) * 256;            // [f][c]
    const float* wr2 = weight + ((size_t)(t2 * 10 + t1) * 5 + l3) * 256;
    float acc = 0.f;
    for (int b = 0; b < 16; b++) {
      float cu = (u < 3) ? s_colg[u * 16 + b] : (u < 5) ? p_colg[(u - 3) * 16 + b] : d_colg[b];
      float cv = (v < 3) ? s_colg[v * 16 + b] : (v < 5) ? p_colg[(v - 3) * 16 + b] : d_colg[b];
      acc += cu * cv * (wr1[b * 16 + c] + wr2[b * 16 + c]);
    }
    ws[idx] = acc;
  } else if (idx < VT_FLOATS + WT_FLOATS) {
    // wt[l][kq][f][kk] = w_rad[l][kq*4+kk][f]
    int o = idx - VT_FLOATS;
    int kk = o & 3, f = (o >> 2) & 15, kq = (o >> 6) & 7, l = o >> 9;
    ws[idx] = w_rad[l * 512 + (kq * 4 + kk) * 16 + f];
  }
}

__global__ __launch_bounds__(256, 5) void outlayer_kernel(
    const float* __restrict__ c0, const float* __restrict__ c1,
    const float* __restrict__ c2, const float* __restrict__ c3,
    const float* __restrict__ c4, const float* __restrict__ R,
    const float* __restrict__ vt, const float* __restrict__ wt,
    const int* __restrict__ Z, const int* __restrict__ api,
    const int* __restrict__ aidx, float* __restrict__ out) {
  __shared__ __align__(16) float s_cg[1104];
  __shared__ __align__(16) float s_buf[16 * PSTRIDE];
  // total LDS: 4416 + 25600 = 30016 B  -> 5 blocks/CU

  const int tid = threadIdx.x;

  for (int e = tid; e < 1104; e += 256) s_cg[e] = g_tab.cg[e];
  __syncthreads();  // the only block-wide barrier

  const int grp = tid >> 4;
  const int lane = tid & 15;            // feature index c
  const int p = blockIdx.x * 16 + grp;  // P = 50000 = 3125*16 exactly
  float* sb = s_buf + grp * PSTRIDE;    // per-pair region, wave-local
  float* sbD = sb + SBD_OFF;            // overlays h rows x>=13 (dead by then)

  const int2 pij = *(const int2*)(api + 2 * p);
  const int i = pij.x, j = pij.y;
  const int ai = aidx[p];
  const int2 aij = *(const int2*)(api + 2 * ai);
  const int t1 = Z[aij.x], t2 = Z[aij.y];

  // ---- radial basis ----
  float dx = R[3 * i + 0] - R[3 * j + 0];
  float dy = R[3 * i + 1] - R[3 * j + 1];
  float dz = R[3 * i + 2] - R[3 * j + 2];
  float d = sqrtf(dx * dx + dy * dy + dz * dz);
  float env = 0.0f;
  if (d < 5.0f) env = 0.5f * (__cosf(PI_F * d * 0.2f) + 1.0f);
  float th = PI_F * d * 0.2f;
  float rlo = __sinf((float)(lane + 1) * th) * env;   // rbf[lane]
  float rhi = __sinf((float)(lane + 17) * th) * env;  // rbf[lane+16]

  // broadcast all 32 rbf values into registers (shfl over the 16-group)
  float rb[32];
#pragma unroll
  for (int k = 0; k < 16; k++) {
    rb[k] = __shfl(rlo, k, 16);
    rb[k + 16] = __shfl(rhi, k, 16);
  }

  // g[l][c=lane] = sum_k rb[k] * wt[l][k][lane]  (8 float4 loads per l)
  float gl[5];
  const float4* wt4 = (const float4*)wt;  // wt4[(l*8+kq)*16 + f]
#pragma unroll
  for (int l = 0; l < 5; l++) {
    float a0 = 0.f, a1 = 0.f, a2 = 0.f, a3 = 0.f;
#pragma unroll
    for (int kq = 0; kq < 8; kq++) {
      float4 w = wt4[(l * 8 + kq) * 16 + lane];
      a0 += w.x * rb[kq * 4 + 0];
      a1 += w.y * rb[kq * 4 + 1];
      a2 += w.z * rb[kq * 4 + 2];
      a3 += w.w * rb[kq * 4 + 3];
    }
    gl[l] = (a0 + a1) + (a2 + a3);
  }

  // ---- Phase A: h[x][c=lane] = g[l][lane]*(ci[m]+cj[m]), chunk-rotated ----
  const float* cl[5] = {c0, c1, c2, c3, c4};
#pragma unroll
  for (int l = 0; l < 5; l++) {
    const int nm = 2 * l + 1;
    const float* ci = cl[l] + ((size_t)i * 16 + lane) * nm;
    const float* cj = cl[l] + ((size_t)j * 16 + lane) * nm;
    float s[9];
    if (l == 0) {
      s[0] = ci[0] + cj[0];
    } else if (l == 1) {
      v2f a = *(const v2f*)ci, b = *(const v2f*)cj;
      s[0] = a[0] + b[0]; s[1] = a[1] + b[1]; s[2] = ci[2] + cj[2];
    } else if (l == 2) {
      v4f a = *(const v4f*)ci, b = *(const v4f*)cj;
      s[0] = a[0] + b[0]; s[1] = a[1] + b[1];
      s[2] = a[2] + b[2]; s[3] = a[3] + b[3];
      s[4] = ci[4] + cj[4];
    } else if (l == 3) {
      v4f a = *(const v4f*)ci, b = *(const v4f*)cj;
      v2f a2 = *(const v2f*)(ci + 4), b2 = *(const v2f*)(cj + 4);
      s[0] = a[0] + b[0]; s[1] = a[1] + b[1];
      s[2] = a[2] + b[2]; s[3] = a[3] + b[3];
      s[4] = a2[0] + b2[0]; s[5] = a2[1] + b2[1];
      s[6] = ci[6] + cj[6];
    } else {
      v4f a = *(const v4f*)ci, b = *(const v4f*)cj;
      v4f a2 = *(const v4f*)(ci + 4), b2 = *(const v4f*)(cj + 4);
      s[0] = a[0] + b[0]; s[1] = a[1] + b[1];
      s[2] = a[2] + b[2]; s[3] = a[3] + b[3];
      s[4] = a2[0] + b2[0]; s[5] = a2[1] + b2[1];
      s[6] = a2[2] + b2[2]; s[7] = a2[3] + b2[3];
      s[8] = ci[8] + cj[8];
    }
#pragma unroll
    for (int m = 0; m < nm; m++) {
      int x = l * l + m;
      sb[x * 16 + ((lane + 4 * (x >> 1)) & 15)] = gl[l] * s[m];
    }
  }
  __builtin_amdgcn_wave_barrier();  // wave-local ordering fence (no-op inst)

  // ---- Phase Dtab (into regs): dt = sum_c v[(t1,t2)][e(t)][c] * h[x(t)][c] ----
  float dt[9];
  int dm[9];
  const float* vrow = vt + (size_t)(t1 * 10 + t2) * (NE * 16);
#pragma unroll
  for (int it = 0; it < 9; it++) {
    int t = it * 16 + lane;
    dt[it] = 0.f;
    dm[it] = SBD_LEN;  // parked (unused slot guard, never written)
    if (t < 133) {
      int pc = (int)g_tab.tabC[t];  // 16 consecutive dwords, L1-hot
      int e = pc & 255, x = (pc >> 8) & 255;
      dm[it] = pc >> 16;
      int rotC = 4 * (x >> 1);
      const float* vp = vrow + e * 16;        // global, L1/L2-hot (2.6KB/row)
      const float* crow = &sb[x * 16];
      float acc0 = 0.f, acc1 = 0.f;
#pragma unroll
      for (int q = 0; q < 4; q++) {
        float4 vv = *(const float4*)(vp + 4 * q);
        float4 cv = *(const float4*)&crow[(4 * q + rotC) & 15];
        float t4 = vv.x * cv.x + vv.y * cv.y + vv.z * cv.z + vv.w * cv.w;
        if (q & 1) acc1 += t4; else acc0 += t4;
      }
      dt[it] = acc0 + acc1;
    }
  }
  // all h reads above are older LDS ops than the writes below (in-order pipe)
  __builtin_amdgcn_wave_barrier();
  // zero all 192 padded slots, then scatter the 133 values
#pragma unroll
  for (int s = 0; s < 12; s++) sbD[s * 16 + lane] = 0.f;
  __builtin_amdgcn_wave_barrier();
#pragma unroll
  for (int it = 0; it < 9; it++) {
    int t = it * 16 + lane;
    if (t < 133) sbD[dm[it]] = dt[it];
  }
  __builtin_amdgcn_wave_barrier();

  // ---- Phase D': out elem = cg row . Dtab slice (both padded, b128 reads) ----
#pragma unroll
  for (int it = 0; it < 9; it++) {
    int t = it * 16 + lane;
    if (t < 133) {
      int4 td = *((const int4*)g_tab.tabD + t);  // 16 consecutive int4, L1-hot
      int goff = td.x & 0xffff, n4 = td.x >> 16, doff = td.y;
      const float* cgp = &s_cg[goff];   // 16B-aligned padded row
      const float* dp = &sbD[doff];     // 16B-aligned padded slice (broadcast)
      float a0 = 0.f, a1 = 0.f, a2 = 0.f, a3 = 0.f;
      for (int q4 = 0; q4 < n4; q4++) {
        float4 cgv = *(const float4*)(cgp + 4 * q4);
        float4 dv = *(const float4*)(dp + 4 * q4);
        a0 += cgv.x * dv.x;
        a1 += cgv.y * dv.y;
        a2 += cgv.z * dv.z;
        a3 += cgv.w * dv.w;
      }
      float acc = (a0 + a1) + (a2 + a3);
      sb[td.z] = acc;
      sb[td.w] = acc;  // transpose copy (== td.z on diagonal blocks)
    }
  }
  __builtin_amdgcn_wave_barrier();

  // ---- coalesced float4 writeout of the staged 196 floats ----
  float* outp = out + (size_t)p * 196;
#pragma unroll
  for (int r = 0; r < 4; r++) {
    int idx = r * 16 + lane;
    if (idx < 49) {
      float4 v = *(const float4*)&sb[idx * 4];
      *(float4*)(outp + idx * 4) = v;
    }
  }
}

// ===========================================================================
// Fallback (no workspace): r9-style phases B/C' in-kernel, adapted to the
// padded cg/tabD tables. Only used if ws_size < 272640 B (never observed).
// ===========================================================================
#define FBSTRIDE 592  // 0..399 h/co, 400..591 padded sbD

__global__ __launch_bounds__(256, 3) void outlayer_fb(
    const float* __restrict__ c0, const float* __restrict__ c1,
    const float* __restrict__ c2, const float* __restrict__ c3,
    const float* __restrict__ c4, const float* __restrict__ R,
    const float* __restrict__ w_rad, const float* __restrict__ weight,
    const float* __restrict__ s_colg, const float* __restrict__ p_colg,
    const float* __restrict__ d_colg, const int* __restrict__ Z,
    const int* __restrict__ api, const int* __restrict__ aidx,
    float* __restrict__ out) {
  __shared__ __align__(16) float s_cg[1104];
  __shared__ __align__(16) float s_w6[36 * 16];
  __shared__ __align__(16) float s_buf[16 * FBSTRIDE];

  const int tid = threadIdx.x;
  for (int e = tid; e < 1104; e += 256) s_cg[e] = g_tab.cg[e];
  for (int idx = tid; idx < 576; idx += 256) {
    int comb = idx >> 4, f = idx & 15;
    int u = comb / 6, v = comb % 6;
    float cu = (u < 3) ? s_colg[u * 16 + f] : (u < 5) ? p_colg[(u - 3) * 16 + f] : d_colg[f];
    float cv = (v < 3) ? s_colg[v * 16 + f] : (v < 5) ? p_colg[(v - 3) * 16 + f] : d_colg[f];
    s_w6[comb * 16 + ((f + 4 * (comb >> 1)) & 15)] = cu * cv;
  }
  __syncthreads();

  const int grp = tid >> 4;
  const int lane = tid & 15;
  const int p = blockIdx.x * 16 + grp;
  float* sb = s_buf + grp * FBSTRIDE;
  float* sbD = sb + 400;

  const int2 pij = *(const int2*)(api + 2 * p);
  const int i = pij.x, j = pij.y;
  const int ai = aidx[p];
  const int2 aij = *(const int2*)(api + 2 * ai);
  const int t1 = Z[aij.x], t2 = Z[aij.y];

  float dx = R[3 * i + 0] - R[3 * j + 0];
  float dy = R[3 * i + 1] - R[3 * j + 1];
  float dz = R[3 * i + 2] - R[3 * j + 2];
  float d = sqrtf(dx * dx + dy * dy + dz * dz);
  float env = 0.0f;
  if (d < 5.0f) env = 0.5f * (__cosf(PI_F * d * 0.2f) + 1.0f);
  float th = PI_F * d * 0.2f;
  float rlo = __sinf((float)(lane + 1) * th) * env;
  float rhi = __sinf((float)(lane + 17) * th) * env;

  float gl[5] = {0.f, 0.f, 0.f, 0.f, 0.f};
#pragma unroll
  for (int k = 0; k < 16; k++) {
    float rv = __shfl(rlo, k, 16);
#pragma unroll
    for (int l = 0; l < 5; l++) gl[l] += rv * w_rad[l * 512 + k * 16 + lane];
  }
#pragma unroll
  for (int k = 0; k < 16; k++) {
    float rv = __shfl(rhi, k, 16);
#pragma unroll
    for (int l = 0; l < 5; l++) gl[l] += rv * w_rad[l * 512 + (k + 16) * 16 + lane];
  }

  const float* cl[5] = {c0, c1, c2, c3, c4};
#pragma unroll
  for (int l = 0; l < 5; l++) {
    const int nm = 2 * l + 1;
    const float* ci = cl[l] + ((size_t)i * 16 + lane) * nm;
    const float* cj = cl[l] + ((size_t)j * 16 + lane) * nm;
    float* hb = sb + 16 * l * l;
#pragma unroll
    for (int m = 0; m < 2 * l + 1; m++)
      hb[m * 16 + lane] = gl[l] * (ci[m] + cj[m]);
  }
  __builtin_amdgcn_wave_barrier();

  float co[25];
#pragma unroll
  for (int x = 0; x < 25; x++) co[x] = 0.f;
  const float* w1 = weight + (size_t)(t1 * 10 + t2) * 1280 + lane * 16;
  const float* w2 = weight + (size_t)(t2 * 10 + t1) * 1280 + lane * 16;
#pragma unroll
  for (int l = 0; l < 5; l++) {
    float gwreg[16];
#pragma unroll
    for (int cq = 0; cq < 4; cq++) {
      float4 a4 = *(const float4*)(w1 + l * 256 + cq * 4);
      float4 b4 = *(const float4*)(w2 + l * 256 + cq * 4);
      gwreg[cq * 4 + 0] = a4.x + b4.x;
      gwreg[cq * 4 + 1] = a4.y + b4.y;
      gwreg[cq * 4 + 2] = a4.z + b4.z;
      gwreg[cq * 4 + 3] = a4.w + b4.w;
    }
#pragma unroll
    for (int m = 0; m < 2 * l + 1; m++) {
      const float* hb = &sb[16 * l * l + m * 16];
      float acc = co[l * l + m];
#pragma unroll
      for (int cq = 0; cq < 4; cq++) {
        float4 h4 = *(const float4*)(hb + cq * 4);
        acc += gwreg[cq * 4 + 0] * h4.x + gwreg[cq * 4 + 1] * h4.y +
               gwreg[cq * 4 + 2] * h4.z + gwreg[cq * 4 + 3] * h4.w;
      }
      co[l * l + m] = acc;
    }
  }
  __builtin_amdgcn_wave_barrier();

#pragma unroll
  for (int x = 0; x < 25; x++) sb[x * 16 + ((lane + 4 * (x >> 1)) & 15)] = co[x];
  // zero padded sbD (region disjoint from co rows in fallback layout)
#pragma unroll
  for (int s = 0; s < 12; s++) sbD[s * 16 + lane] = 0.f;
  __builtin_amdgcn_wave_barrier();

#pragma unroll
  for (int it = 0; it < 9; it++) {
    int t = it * 16 + lane;
    if (t < 133) {
      int pc = (int)g_tab.tabC[t];
      int e = pc & 255, x = (pc >> 8) & 255;
      int dmap = pc >> 16;
      int et = g_tab.eTab[e];
      int comb = et & 255;
      int rotW = 4 * (comb >> 1), rotC = 4 * (x >> 1);
      const float* wrow = &s_w6[comb * 16];
      const float* crow = &sb[x * 16];
      float acc0 = 0.f, acc1 = 0.f;
#pragma unroll
      for (int q = 0; q < 4; q++) {
        float4 wv = *(const float4*)&wrow[(4 * q + rotW) & 15];
        float4 cv = *(const float4*)&crow[(4 * q + rotC) & 15];
        float t4 = wv.x * cv.x + wv.y * cv.y + wv.z * cv.z + wv.w * cv.w;
        if (q & 1) acc1 += t4; else acc0 += t4;
      }
      sbD[dmap] = acc0 + acc1;
    }
  }
  __builtin_amdgcn_wave_barrier();

#pragma unroll
  for (int it = 0; it < 9; it++) {
    int t = it * 16 + lane;
    if (t < 133) {
      int4 td = *((const int4*)g_tab.tabD + t);
      int goff = td.x & 0xffff, n4 = td.x >> 16, doff = td.y;
      const float* cgp = &s_cg[goff];
      const float* dp = &sbD[doff];
      float a0 = 0.f, a1 = 0.f, a2 = 0.f, a3 = 0.f;
      for (int q4 = 0; q4 < n4; q4++) {
        float4 cgv = *(const float4*)(cgp + 4 * q4);
        float4 dv = *(const float4*)(dp + 4 * q4);
        a0 += cgv.x * dv.x;
        a1 += cgv.y * dv.y;
        a2 += cgv.z * dv.z;
        a3 += cgv.w * dv.w;
      }
      float acc = (a0 + a1) + (a2 + a3);
      sb[td.z] = acc;
      sb[td.w] = acc;
    }
  }
  __builtin_amdgcn_wave_barrier();

  float* outp = out + (size_t)p * 196;
#pragma unroll
  for (int r = 0; r < 4; r++) {
    int idx = r * 16 + lane;
    if (idx < 49) {
      float4 v = *(const float4*)&sb[idx * 4];
      *(float4*)(outp + idx * 4) = v;
    }
  }
}

// ===========================================================================
// Launch: vtab+wt pre-kernel (272KB into d_ws) + fused main kernel.
// No host sync, graph-capture safe.
// ===========================================================================
extern "C" void kernel_launch(void* const* d_in, const int* in_sizes, int n_in,
                              void* d_out, int out_size, void* d_ws, size_t ws_size,
                              hipStream_t stream) {
  (void)in_sizes; (void)n_in; (void)out_size;

  const float* c0 = (const float*)d_in[0];
  const float* c1 = (const float*)d_in[1];
  const float* c2 = (const float*)d_in[2];
  const float* c3 = (const float*)d_in[3];
  const float* c4 = (const float*)d_in[4];
  const float* R = (const float*)d_in[5];
  const float* w_rad = (const float*)d_in[6];
  const float* weight = (const float*)d_in[7];
  const float* s_col = (const float*)d_in[8];
  const float* p_col = (const float*)d_in[9];
  const float* d_col = (const float*)d_in[10];
  const int* Z = (const int*)d_in[11];
  const int* api = (const int*)d_in[12];
  const int* aidx = (const int*)d_in[13];

  dim3 grid(3125), block(256);
  const int ws_floats = VT_FLOATS + WT_FLOATS;            // 68160
  const size_t ws_bytes = (size_t)ws_floats * sizeof(float);  // 272640

  if (d_ws != nullptr && ws_size >= ws_bytes) {
    float* wsp = (float*)d_ws;
    hipLaunchKernelGGL(vtab_kernel, dim3((ws_floats + 255) / 256), dim3(256),
                       0, stream, weight, w_rad, s_col, p_col, d_col, wsp);
    hipLaunchKernelGGL(outlayer_kernel, grid, block, 0, stream,
                       c0, c1, c2, c3, c4, R, (const float*)wsp,
                       (const float*)(wsp + VT_FLOATS),
                       Z, api, aidx, (float*)d_out);
  } else {
    hipLaunchKernelGGL(outlayer_fb, grid, block, 0, stream,
                       c0, c1, c2, c3, c4, R, w_rad, weight,
                       s_col, p_col, d_col, Z, api, aidx, (float*)d_out);
  }
}

// Round 7
// 159.671 us; speedup vs baseline: 2.7453x; 2.7453x over previous
//
#include <hip/hip_runtime.h>
#include <cstdint>

#define PI_F 3.14159265358979323846f

// ===========================================================================
// Compile-time reproduction of np.random.RandomState(seed).standard_normal
// (MT19937 + legacy Marsaglia polar gauss).
// Packing (r11/r12): cg rows padded to mult-of-4 floats (zero-filled) ->
// cg[1104]; Dtab slices padded likewise (192 padded slots). tabC[t] =
// e | x<<8 | dmap<<16 (dmap = padded writeback slot). tabD[ei] =
// {goff_p|n4<<16, doff_p, p1, p2}, n4 = padded_len/4. eTab[41] = comb|l3<<8.
// ===========================================================================
namespace cgc {

constexpr double csqrt(double x) {
  if (x <= 0.0) return 0.0;
  double m = x; int e = 0;
  while (m >= 4.0) { m *= 0.25; e++; }
  while (m < 1.0) { m *= 4.0; e--; }
  double g = 1.5;
  for (int i = 0; i < 16; i++) g = 0.5 * (g + m / g);
  double s = g;
  if (e > 0) for (int i = 0; i < e; i++) s *= 2.0;
  else       for (int i = 0; i < -e; i++) s *= 0.5;
  return s;
}

constexpr double clog(double x) {
  int k = 0;
  double m = x;
  while (m < 0.7071067811865476) { m *= 2.0; k--; }
  while (m > 1.4142135623730951) { m *= 0.5; k++; }
  double t = (m - 1.0) / (m + 1.0), t2 = t * t, s = 0.0, p = t;
  for (int i = 0; i < 27; i++) { s += p / (double)(2 * i + 1); p *= t2; }
  return 2.0 * s + (double)k * 0.6931471805599453;
}

struct RS { uint32_t mt[624]; int mti; bool has; double g; };

constexpr void rs_seed(RS& r, uint32_t s) {
  for (int i = 0; i < 624; i++) { r.mt[i] = s; s = 1812433253u * (s ^ (s >> 30)) + (uint32_t)i + 1u; }
  r.mti = 624; r.has = false; r.g = 0.0;
}
constexpr uint32_t rs_next(RS& r) {
  if (r.mti >= 624) {
    for (int i = 0; i < 624; i++) {
      uint32_t y = (r.mt[i] & 0x80000000u) | (r.mt[(i + 1) % 624] & 0x7fffffffu);
      r.mt[i] = r.mt[(i + 397) % 624] ^ (y >> 1) ^ ((y & 1u) ? 0x9908b0dfu : 0u);
    }
    r.mti = 0;
  }
  uint32_t y = r.mt[r.mti++];
  y ^= y >> 11; y ^= (y << 7) & 0x9d2c5680u; y ^= (y << 15) & 0xefc60000u; y ^= y >> 18;
  return y;
}
constexpr double rs_dbl(RS& r) {
  uint32_t a = rs_next(r) >> 5, b = rs_next(r) >> 6;
  return ((double)a * 67108864.0 + (double)b) / 9007199254740992.0;
}
constexpr double rs_gauss(RS& r) {
  if (r.has) { r.has = false; return r.g; }
  double x1 = 0, x2 = 0, r2 = 0;
  do {
    x1 = 2.0 * rs_dbl(r) - 1.0;
    x2 = 2.0 * rs_dbl(r) - 1.0;
    r2 = x1 * x1 + x2 * x2;
  } while (r2 >= 1.0 || r2 == 0.0);
  double f = csqrt(-2.0 * clog(r2) / r2);
  r.g = f * x1; r.has = true;
  return f * x2;
}

struct Tab { float v[228]; };

constexpr Tab gen(int l1, int l2, int l3) {
  Tab t{};
  RS r{};
  rs_seed(r, (uint32_t)(1000 + l1 * 100 + l2 * 10 + l3));
  int sz = (2 * l1 + 1) * (2 * l2 + 1) * (2 * l3 + 1);
  for (int k = 0; k < sz; k++) t.v[k] = (float)rs_gauss(r);
  return t;
}

constexpr Tab T000 = gen(0,0,0);
constexpr Tab T101 = gen(1,0,1);
constexpr Tab T110 = gen(1,1,0);
constexpr Tab T111 = gen(1,1,1);
constexpr Tab T112 = gen(1,1,2);
constexpr Tab T202 = gen(2,0,2);
constexpr Tab T211 = gen(2,1,1);
constexpr Tab T212 = gen(2,1,2);
constexpr Tab T213 = gen(2,1,3);
constexpr Tab T220 = gen(2,2,0);
constexpr Tab T221 = gen(2,2,1);
constexpr Tab T222 = gen(2,2,2);
constexpr Tab T223 = gen(2,2,3);
constexpr Tab T224 = gen(2,2,4);

struct alignas(16) Stage {
  int tabD[133 * 4];   // goff_p|n4<<16, doff_p, p1, p2
  float cg[1104];      // padded rows, zero-filled pads
  uint32_t tabC[133];  // e | x<<8 | dmap<<16
  int eTab[48];        // comb | l3<<8
  int ne;              // == 41
};

constexpr Stage make_stage() {
  Stage S{};
  S.ne = 0;
  const Tab* tabs[14] = {&T000,&T101,&T110,&T111,&T112,&T202,&T211,&T212,&T213,
                         &T220,&T221,&T222,&T223,&T224};
  const int KL[14][3] = {{0,0,0},{1,0,1},{1,1,0},{1,1,1},{1,1,2},{2,0,2},{2,1,1},
                         {2,1,2},{2,1,3},{2,2,0},{2,2,1},{2,2,2},{2,2,3},{2,2,4}};
  const int kBk[6][2] = {{0,0},{1,0},{1,1},{2,0},{2,1},{2,2}};

  int cgbase_p[6] = {}, dbase[6] = {}, dbase_p[6] = {}, xlenA[6] = {}, pxlenA[6] = {};
  int offp = 0, doff = 0, doffp = 0;
  for (int bk = 0; bk < 6; bk++) {
    int l1 = kBk[bk][0], l2 = kBk[bk][1];
    int M = 2 * l1 + 1, N = 2 * l2 + 1;
    int Ar = (l1 == 0) ? 3 : (l1 == 1) ? 2 : 1;
    int Br = (l2 == 0) ? 3 : (l2 == 1) ? 2 : 1;
    int xs[25] = {}, xl3[25] = {}, xa[25] = {};
    int cnt = 0;
    for (int l3 = l1 - l2; l3 <= l1 + l2; l3++)
      for (int a = 0; a < 2 * l3 + 1; a++) {
        xs[cnt] = l3 * l3 + a; xl3[cnt] = l3; xa[cnt] = a; cnt++;
      }
    int xlen = cnt;
    int pxlen = ((xlen + 3) / 4) * 4;
    xlenA[bk] = xlen; pxlenA[bk] = pxlen;
    cgbase_p[bk] = offp; dbase[bk] = doff; dbase_p[bk] = doffp;
    for (int mn = 0; mn < M * N; mn++)
      for (int xi = 0; xi < xlen; xi++) {
        int l3 = xl3[xi], K3 = 2 * l3 + 1, ti = 0;
        for (int c = 0; c < 14; c++)
          if (KL[c][0] == l1 && KL[c][1] == l2 && KL[c][2] == l3) ti = c;
        S.cg[offp + mn * pxlen + xi] = tabs[ti]->v[mn * K3 + xa[xi]];
      }
    offp += M * N * pxlen;
    for (int q = 0; q < Ar * Br; q++) {
      int a = q / Br, b = q % Br;
      int u = (l1 == 0) ? a : (l1 == 1) ? 3 + a : 5;
      int v = (l2 == 0) ? b : (l2 == 1) ? 3 + b : 5;
      int comb = u * 6 + v;
      for (int xi = 0; xi < xlen; xi++) {
        int key = comb | (xl3[xi] << 8);
        int id = -1;
        for (int s = 0; s < S.ne; s++) if (S.eTab[s] == key) { id = s; break; }
        if (id < 0) { id = S.ne; S.eTab[S.ne] = key; S.ne++; }
        int dmap = dbase_p[bk] + q * pxlen + xi;  // padded writeback slot
        S.tabC[doff + q * xlen + xi] = (uint32_t)(id | (xs[xi] << 8) | (dmap << 16));
      }
    }
    doff += Ar * Br * xlen;
    doffp += Ar * Br * pxlen;
  }
  const int ord[6] = {5, 4, 2, 3, 1, 0};  // big xlen first
  int ei = 0;
  for (int bo = 0; bo < 6; bo++) {
    int bk = ord[bo];
    int l1 = kBk[bk][0], l2 = kBk[bk][1];
    int M = 2 * l1 + 1, N = 2 * l2 + 1;
    int Ar = (l1 == 0) ? 3 : (l1 == 1) ? 2 : 1;
    int Br = (l2 == 0) ? 3 : (l2 == 1) ? 2 : 1;
    int rb1 = (l1 == 0) ? 0 : (l1 == 1) ? 3 : 9;
    int rb2 = (l2 == 0) ? 0 : (l2 == 1) ? 3 : 9;
    int colDim = N * Br, pxlen = pxlenA[bk];
    for (int e = 0; e < M * N * Ar * Br; e++) {
      int b = e % Br, t2 = e / Br;
      int a = t2 % Ar; t2 /= Ar;
      int n = t2 % N, m = t2 / N;
      int mn = m * N + n, q = a * Br + b;
      int ri = e / colDim, ci = e % colDim;
      int p1 = (rb1 + ri) * 14 + (rb2 + ci);
      int p2 = (l1 == l2) ? p1 : ((rb2 + ci) * 14 + (rb1 + ri));
      S.tabD[4 * ei + 0] = (cgbase_p[bk] + mn * pxlen) | ((pxlen / 4) << 16);
      S.tabD[4 * ei + 1] = dbase_p[bk] + q * pxlen;
      S.tabD[4 * ei + 2] = p1;
      S.tabD[4 * ei + 3] = p2;
      ei++;
    }
  }
  return S;
}

constexpr Stage ST = make_stage();
static_assert(ST.ne == 41, "expected 41 distinct (comb,l3) pairs");

}  // namespace cgc

__device__ const cgc::Stage g_tab = cgc::ST;

#define NE 41
#define VT_FLOATS (100 * NE * 16)   // 65600
#define SBD_LEN 192                 // padded Dtab slots

// align-4 vector types for unaligned global float4/float2 loads
typedef float v4f __attribute__((vector_size(16), aligned(4)));
typedef float v2f __attribute__((vector_size(8), aligned(4)));

// ===========================================================================
// r12: UNBUNDLE r11. r11 regressed 67->368us with WRITE_SIZE 44->657MB =
// scratch spill (rb[32] g-loop rewrite blew the 5-wave VGPR budget).
// r12 = r10 base (inline-shfl g-loop, scalar w_rad loads — proven 67us,
// no spill) + ONLY the padded-D' change from r11:
//   cg rows and Dtab slices padded to mult-of-4, 16B-aligned => D' dot is
//   2x ds_read_b128 + 4 FMA per step (214 scalar b32 -> ~64 b128 per wave).
// Register additions vs r10: dm[9] only.
// Verification signal: WRITE_SIZE must return to ~44MB (spill gone).
// ===========================================================================
#define PSTRIDE 400   // h rows x=0..24 at 0..399; sbD overlays 200..391
#define SBD_OFF 200

__global__ __launch_bounds__(256) void vtab_kernel(
    const float* __restrict__ weight, const float* __restrict__ s_colg,
    const float* __restrict__ p_colg, const float* __restrict__ d_colg,
    float* __restrict__ vt) {
  int idx = blockIdx.x * 256 + threadIdx.x;  // 100*41*16 = 65600
  if (idx >= VT_FLOATS) return;
  int c = idx & 15;
  int rest = idx >> 4;
  int e = rest % NE, row = rest / NE;
  int t1 = row / 10, t2 = row - t1 * 10;
  int et = g_tab.eTab[e];
  int comb = et & 255, l3 = et >> 8;
  int u = comb / 6, v = comb % 6;
  const float* wr1 = weight + ((size_t)row * 5 + l3) * 256;            // [f][c]
  const float* wr2 = weight + ((size_t)(t2 * 10 + t1) * 5 + l3) * 256;
  float acc = 0.f;
  for (int b = 0; b < 16; b++) {
    float cu = (u < 3) ? s_colg[u * 16 + b] : (u < 5) ? p_colg[(u - 3) * 16 + b] : d_colg[b];
    float cv = (v < 3) ? s_colg[v * 16 + b] : (v < 5) ? p_colg[(v - 3) * 16 + b] : d_colg[b];
    acc += cu * cv * (wr1[b * 16 + c] + wr2[b * 16 + c]);
  }
  vt[idx] = acc;  // layout [row][e][c]
}

__global__ __launch_bounds__(256, 5) void outlayer_kernel(
    const float* __restrict__ c0, const float* __restrict__ c1,
    const float* __restrict__ c2, const float* __restrict__ c3,
    const float* __restrict__ c4, const float* __restrict__ R,
    const float* __restrict__ w_rad, const float* __restrict__ vt,
    const int* __restrict__ Z, const int* __restrict__ api,
    const int* __restrict__ aidx, float* __restrict__ out) {
  __shared__ __align__(16) float s_cg[1104];
  __shared__ __align__(16) float s_buf[16 * PSTRIDE];
  // total LDS: 4416 + 25600 = 30016 B  -> 5 blocks/CU

  const int tid = threadIdx.x;

  for (int e = tid; e < 1104; e += 256) s_cg[e] = g_tab.cg[e];
  __syncthreads();  // the only block-wide barrier

  const int grp = tid >> 4;
  const int lane = tid & 15;            // feature index c
  const int p = blockIdx.x * 16 + grp;  // P = 50000 = 3125*16 exactly
  float* sb = s_buf + grp * PSTRIDE;    // per-pair region, wave-local
  float* sbD = sb + SBD_OFF;            // overlays h rows x>=13 (dead by then)

  const int2 pij = *(const int2*)(api + 2 * p);
  const int i = pij.x, j = pij.y;
  const int ai = aidx[p];
  const int2 aij = *(const int2*)(api + 2 * ai);
  const int t1 = Z[aij.x], t2 = Z[aij.y];

  // ---- radial basis ----
  float dx = R[3 * i + 0] - R[3 * j + 0];
  float dy = R[3 * i + 1] - R[3 * j + 1];
  float dz = R[3 * i + 2] - R[3 * j + 2];
  float d = sqrtf(dx * dx + dy * dy + dz * dz);
  float env = 0.0f;
  if (d < 5.0f) env = 0.5f * (__cosf(PI_F * d * 0.2f) + 1.0f);
  float th = PI_F * d * 0.2f;
  float rlo = __sinf((float)(lane + 1) * th) * env;   // rbf[lane]
  float rhi = __sinf((float)(lane + 17) * th) * env;  // rbf[lane+16]

  // g[l][c=lane] = sum_k rbf[k] * w_rad[l,k,c]  (r10-proven form, no rb[] array)
  float gl[5] = {0.f, 0.f, 0.f, 0.f, 0.f};
#pragma unroll
  for (int k = 0; k < 16; k++) {
    float rv = __shfl(rlo, k, 16);
#pragma unroll
    for (int l = 0; l < 5; l++) gl[l] += rv * w_rad[l * 512 + k * 16 + lane];
  }
#pragma unroll
  for (int k = 0; k < 16; k++) {
    float rv = __shfl(rhi, k, 16);
#pragma unroll
    for (int l = 0; l < 5; l++) gl[l] += rv * w_rad[l * 512 + (k + 16) * 16 + lane];
  }

  // ---- Phase A: h[x][c=lane] = g[l][lane]*(ci[m]+cj[m]), chunk-rotated ----
  const float* cl[5] = {c0, c1, c2, c3, c4};
#pragma unroll
  for (int l = 0; l < 5; l++) {
    const int nm = 2 * l + 1;
    const float* ci = cl[l] + ((size_t)i * 16 + lane) * nm;
    const float* cj = cl[l] + ((size_t)j * 16 + lane) * nm;
    float s[9];
    if (l == 0) {
      s[0] = ci[0] + cj[0];
    } else if (l == 1) {
      v2f a = *(const v2f*)ci, b = *(const v2f*)cj;
      s[0] = a[0] + b[0]; s[1] = a[1] + b[1]; s[2] = ci[2] + cj[2];
    } else if (l == 2) {
      v4f a = *(const v4f*)ci, b = *(const v4f*)cj;
      s[0] = a[0] + b[0]; s[1] = a[1] + b[1];
      s[2] = a[2] + b[2]; s[3] = a[3] + b[3];
      s[4] = ci[4] + cj[4];
    } else if (l == 3) {
      v4f a = *(const v4f*)ci, b = *(const v4f*)cj;
      v2f a2 = *(const v2f*)(ci + 4), b2 = *(const v2f*)(cj + 4);
      s[0] = a[0] + b[0]; s[1] = a[1] + b[1];
      s[2] = a[2] + b[2]; s[3] = a[3] + b[3];
      s[4] = a2[0] + b2[0]; s[5] = a2[1] + b2[1];
      s[6] = ci[6] + cj[6];
    } else {
      v4f a = *(const v4f*)ci, b = *(const v4f*)cj;
      v4f a2 = *(const v4f*)(ci + 4), b2 = *(const v4f*)(cj + 4);
      s[0] = a[0] + b[0]; s[1] = a[1] + b[1];
      s[2] = a[2] + b[2]; s[3] = a[3] + b[3];
      s[4] = a2[0] + b2[0]; s[5] = a2[1] + b2[1];
      s[6] = a2[2] + b2[2]; s[7] = a2[3] + b2[3];
      s[8] = ci[8] + cj[8];
    }
#pragma unroll
    for (int m = 0; m < nm; m++) {
      int x = l * l + m;
      sb[x * 16 + ((lane + 4 * (x >> 1)) & 15)] = gl[l] * s[m];
    }
  }
  __builtin_amdgcn_wave_barrier();  // wave-local ordering fence (no-op inst)

  // ---- Phase Dtab (into regs): dt = sum_c v[(t1,t2)][e(t)][c] * h[x(t)][c] ----
  float dt[9];
  int dm[9];
  const float* vrow = vt + (size_t)(t1 * 10 + t2) * (NE * 16);
#pragma unroll
  for (int it = 0; it < 9; it++) {
    int t = it * 16 + lane;
    dt[it] = 0.f;
    dm[it] = 0;
    if (t < 133) {
      int pc = (int)g_tab.tabC[t];  // 16 consecutive dwords, L1-hot
      int e = pc & 255, x = (pc >> 8) & 255;
      dm[it] = pc >> 16;
      int rotC = 4 * (x >> 1);
      const float* vp = vrow + e * 16;        // global, L1/L2-hot (2.6KB/row)
      const float* crow = &sb[x * 16];
      float acc0 = 0.f, acc1 = 0.f;
#pragma unroll
      for (int q = 0; q < 4; q++) {
        float4 vv = *(const float4*)(vp + 4 * q);
        float4 cv = *(const float4*)&crow[(4 * q + rotC) & 15];
        float t4 = vv.x * cv.x + vv.y * cv.y + vv.z * cv.z + vv.w * cv.w;
        if (q & 1) acc1 += t4; else acc0 += t4;
      }
      dt[it] = acc0 + acc1;
    }
  }
  // all h reads above are older LDS ops than the writes below (in-order pipe)
  __builtin_amdgcn_wave_barrier();
  // zero all 192 padded slots, then scatter the 133 values
#pragma unroll
  for (int s = 0; s < 12; s++) sbD[s * 16 + lane] = 0.f;
  __builtin_amdgcn_wave_barrier();
#pragma unroll
  for (int it = 0; it < 9; it++) {
    int t = it * 16 + lane;
    if (t < 133) sbD[dm[it]] = dt[it];
  }
  __builtin_amdgcn_wave_barrier();

  // ---- Phase D': out elem = cg row . Dtab slice (both padded, b128 reads) ----
#pragma unroll
  for (int it = 0; it < 9; it++) {
    int t = it * 16 + lane;
    if (t < 133) {
      int4 td = *((const int4*)g_tab.tabD + t);  // 16 consecutive int4, L1-hot
      int goff = td.x & 0xffff, n4 = td.x >> 16, doff = td.y;
      const float* cgp = &s_cg[goff];   // 16B-aligned padded row
      const float* dp = &sbD[doff];     // 16B-aligned padded slice
      float a0 = 0.f, a1 = 0.f, a2 = 0.f, a3 = 0.f;
      for (int q4 = 0; q4 < n4; q4++) {
        float4 cgv = *(const float4*)(cgp + 4 * q4);
        float4 dv = *(const float4*)(dp + 4 * q4);
        a0 += cgv.x * dv.x;
        a1 += cgv.y * dv.y;
        a2 += cgv.z * dv.z;
        a3 += cgv.w * dv.w;
      }
      float acc = (a0 + a1) + (a2 + a3);
      sb[td.z] = acc;
      sb[td.w] = acc;  // transpose copy (== td.z on diagonal blocks)
    }
  }
  __builtin_amdgcn_wave_barrier();

  // ---- coalesced float4 writeout of the staged 196 floats ----
  float* outp = out + (size_t)p * 196;
#pragma unroll
  for (int r = 0; r < 4; r++) {
    int idx = r * 16 + lane;
    if (idx < 49) {
      float4 v = *(const float4*)&sb[idx * 4];
      *(float4*)(outp + idx * 4) = v;
    }
  }
}

// ===========================================================================
// Fallback (no workspace): r9-style phases B/C' in-kernel, adapted to the
// padded cg/tabD tables. Only used if ws_size < 262400 B (never observed).
// ===========================================================================
#define FBSTRIDE 592  // 0..399 h/co, 400..591 padded sbD

__global__ __launch_bounds__(256, 3) void outlayer_fb(
    const float* __restrict__ c0, const float* __restrict__ c1,
    const float* __restrict__ c2, const float* __restrict__ c3,
    const float* __restrict__ c4, const float* __restrict__ R,
    const float* __restrict__ w_rad, const float* __restrict__ weight,
    const float* __restrict__ s_colg, const float* __restrict__ p_colg,
    const float* __restrict__ d_colg, const int* __restrict__ Z,
    const int* __restrict__ api, const int* __restrict__ aidx,
    float* __restrict__ out) {
  __shared__ __align__(16) float s_cg[1104];
  __shared__ __align__(16) float s_w6[36 * 16];
  __shared__ __align__(16) float s_buf[16 * FBSTRIDE];

  const int tid = threadIdx.x;
  for (int e = tid; e < 1104; e += 256) s_cg[e] = g_tab.cg[e];
  for (int idx = tid; idx < 576; idx += 256) {
    int comb = idx >> 4, f = idx & 15;
    int u = comb / 6, v = comb % 6;
    float cu = (u < 3) ? s_colg[u * 16 + f] : (u < 5) ? p_colg[(u - 3) * 16 + f] : d_colg[f];
    float cv = (v < 3) ? s_colg[v * 16 + f] : (v < 5) ? p_colg[(v - 3) * 16 + f] : d_colg[f];
    s_w6[comb * 16 + ((f + 4 * (comb >> 1)) & 15)] = cu * cv;
  }
  __syncthreads();

  const int grp = tid >> 4;
  const int lane = tid & 15;
  const int p = blockIdx.x * 16 + grp;
  float* sb = s_buf + grp * FBSTRIDE;
  float* sbD = sb + 400;

  const int2 pij = *(const int2*)(api + 2 * p);
  const int i = pij.x, j = pij.y;
  const int ai = aidx[p];
  const int2 aij = *(const int2*)(api + 2 * ai);
  const int t1 = Z[aij.x], t2 = Z[aij.y];

  float dx = R[3 * i + 0] - R[3 * j + 0];
  float dy = R[3 * i + 1] - R[3 * j + 1];
  float dz = R[3 * i + 2] - R[3 * j + 2];
  float d = sqrtf(dx * dx + dy * dy + dz * dz);
  float env = 0.0f;
  if (d < 5.0f) env = 0.5f * (__cosf(PI_F * d * 0.2f) + 1.0f);
  float th = PI_F * d * 0.2f;
  float rlo = __sinf((float)(lane + 1) * th) * env;
  float rhi = __sinf((float)(lane + 17) * th) * env;

  float gl[5] = {0.f, 0.f, 0.f, 0.f, 0.f};
#pragma unroll
  for (int k = 0; k < 16; k++) {
    float rv = __shfl(rlo, k, 16);
#pragma unroll
    for (int l = 0; l < 5; l++) gl[l] += rv * w_rad[l * 512 + k * 16 + lane];
  }
#pragma unroll
  for (int k = 0; k < 16; k++) {
    float rv = __shfl(rhi, k, 16);
#pragma unroll
    for (int l = 0; l < 5; l++) gl[l] += rv * w_rad[l * 512 + (k + 16) * 16 + lane];
  }

  const float* cl[5] = {c0, c1, c2, c3, c4};
#pragma unroll
  for (int l = 0; l < 5; l++) {
    const int nm = 2 * l + 1;
    const float* ci = cl[l] + ((size_t)i * 16 + lane) * nm;
    const float* cj = cl[l] + ((size_t)j * 16 + lane) * nm;
    float* hb = sb + 16 * l * l;
#pragma unroll
    for (int m = 0; m < 2 * l + 1; m++)
      hb[m * 16 + lane] = gl[l] * (ci[m] + cj[m]);
  }
  __builtin_amdgcn_wave_barrier();

  float co[25];
#pragma unroll
  for (int x = 0; x < 25; x++) co[x] = 0.f;
  const float* w1 = weight + (size_t)(t1 * 10 + t2) * 1280 + lane * 16;
  const float* w2 = weight + (size_t)(t2 * 10 + t1) * 1280 + lane * 16;
#pragma unroll
  for (int l = 0; l < 5; l++) {
    float gwreg[16];
#pragma unroll
    for (int cq = 0; cq < 4; cq++) {
      float4 a4 = *(const float4*)(w1 + l * 256 + cq * 4);
      float4 b4 = *(const float4*)(w2 + l * 256 + cq * 4);
      gwreg[cq * 4 + 0] = a4.x + b4.x;
      gwreg[cq * 4 + 1] = a4.y + b4.y;
      gwreg[cq * 4 + 2] = a4.z + b4.z;
      gwreg[cq * 4 + 3] = a4.w + b4.w;
    }
#pragma unroll
    for (int m = 0; m < 2 * l + 1; m++) {
      const float* hb = &sb[16 * l * l + m * 16];
      float acc = co[l * l + m];
#pragma unroll
      for (int cq = 0; cq < 4; cq++) {
        float4 h4 = *(const float4*)(hb + cq * 4);
        acc += gwreg[cq * 4 + 0] * h4.x + gwreg[cq * 4 + 1] * h4.y +
               gwreg[cq * 4 + 2] * h4.z + gwreg[cq * 4 + 3] * h4.w;
      }
      co[l * l + m] = acc;
    }
  }
  __builtin_amdgcn_wave_barrier();

#pragma unroll
  for (int x = 0; x < 25; x++) sb[x * 16 + ((lane + 4 * (x >> 1)) & 15)] = co[x];
  // zero padded sbD (region disjoint from co rows in fallback layout)
#pragma unroll
  for (int s = 0; s < 12; s++) sbD[s * 16 + lane] = 0.f;
  __builtin_amdgcn_wave_barrier();

#pragma unroll
  for (int it = 0; it < 9; it++) {
    int t = it * 16 + lane;
    if (t < 133) {
      int pc = (int)g_tab.tabC[t];
      int e = pc & 255, x = (pc >> 8) & 255;
      int dmap = pc >> 16;
      int et = g_tab.eTab[e];
      int comb = et & 255;
      int rotW = 4 * (comb >> 1), rotC = 4 * (x >> 1);
      const float* wrow = &s_w6[comb * 16];
      const float* crow = &sb[x * 16];
      float acc0 = 0.f, acc1 = 0.f;
#pragma unroll
      for (int q = 0; q < 4; q++) {
        float4 wv = *(const float4*)&wrow[(4 * q + rotW) & 15];
        float4 cv = *(const float4*)&crow[(4 * q + rotC) & 15];
        float t4 = wv.x * cv.x + wv.y * cv.y + wv.z * cv.z + wv.w * cv.w;
        if (q & 1) acc1 += t4; else acc0 += t4;
      }
      sbD[dmap] = acc0 + acc1;
    }
  }
  __builtin_amdgcn_wave_barrier();

#pragma unroll
  for (int it = 0; it < 9; it++) {
    int t = it * 16 + lane;
    if (t < 133) {
      int4 td = *((const int4*)g_tab.tabD + t);
      int goff = td.x & 0xffff, n4 = td.x >> 16, doff = td.y;
      const float* cgp = &s_cg[goff];
      const float* dp = &sbD[doff];
      float a0 = 0.f, a1 = 0.f, a2 = 0.f, a3 = 0.f;
      for (int q4 = 0; q4 < n4; q4++) {
        float4 cgv = *(const float4*)(cgp + 4 * q4);
        float4 dv = *(const float4*)(dp + 4 * q4);
        a0 += cgv.x * dv.x;
        a1 += cgv.y * dv.y;
        a2 += cgv.z * dv.z;
        a3 += cgv.w * dv.w;
      }
      float acc = (a0 + a1) + (a2 + a3);
      sb[td.z] = acc;
      sb[td.w] = acc;
    }
  }
  __builtin_amdgcn_wave_barrier();

  float* outp = out + (size_t)p * 196;
#pragma unroll
  for (int r = 0; r < 4; r++) {
    int idx = r * 16 + lane;
    if (idx < 49) {
      float4 v = *(const float4*)&sb[idx * 4];
      *(float4*)(outp + idx * 4) = v;
    }
  }
}

// ===========================================================================
// Launch: vtab pre-kernel (262KB into d_ws) + fused main kernel.
// No host sync, graph-capture safe.
// ===========================================================================
extern "C" void kernel_launch(void* const* d_in, const int* in_sizes, int n_in,
                              void* d_out, int out_size, void* d_ws, size_t ws_size,
                              hipStream_t stream) {
  (void)in_sizes; (void)n_in; (void)out_size;

  const float* c0 = (const float*)d_in[0];
  const float* c1 = (const float*)d_in[1];
  const float* c2 = (const float*)d_in[2];
  const float* c3 = (const float*)d_in[3];
  const float* c4 = (const float*)d_in[4];
  const float* R = (const float*)d_in[5];
  const float* w_rad = (const float*)d_in[6];
  const float* weight = (const float*)d_in[7];
  const float* s_col = (const float*)d_in[8];
  const float* p_col = (const float*)d_in[9];
  const float* d_col = (const float*)d_in[10];
  const int* Z = (const int*)d_in[11];
  const int* api = (const int*)d_in[12];
  const int* aidx = (const int*)d_in[13];

  dim3 grid(3125), block(256);
  const size_t vt_bytes = (size_t)VT_FLOATS * sizeof(float);  // 262400

  if (d_ws != nullptr && ws_size >= vt_bytes) {
    float* vt = (float*)d_ws;
    hipLaunchKernelGGL(vtab_kernel, dim3((VT_FLOATS + 255) / 256), dim3(256),
                       0, stream, weight, s_col, p_col, d_col, vt);
    hipLaunchKernelGGL(outlayer_kernel, grid, block, 0, stream,
                       c0, c1, c2, c3, c4, R, w_rad, (const float*)vt,
                       Z, api, aidx, (float*)d_out);
  } else {
    hipLaunchKernelGGL(outlayer_fb, grid, block, 0, stream,
                       c0, c1, c2, c3, c4, R, w_rad, weight,
                       s_col, p_col, d_col, Z, api, aidx, (float*)d_out);
  }
}